// Round 2
// baseline (16397.337 us; speedup 1.0000x reference)
//
#include <hip/hip_runtime.h>
#include <hip/hip_bf16.h>
#include <hip/hip_cooperative_groups.h>
#include <cstdint>
#include <cstddef>

namespace cg = cooperative_groups;

// B=32, T=512, I=H=1024, L=2, gates 4H=4096. fp32 in/out.
// d_out fp32: outputs[32][512][1024] ++ h_n[2][32][1024] ++ c_n[2][32][1024].
// Structure: per chunk of Tc steps:
//   gemm128: G0 = x@Wx0^T + b0 (bf16 MFMA GEMM, fp32 out; Wx0 pre-cast bf16)
//   lstm_persist (cooperative, 192 blocks, grid.sync per timestep):
//     blocks 0..63  : layer-0 recurrence, 64 weight rows x K=1024 in LDS
//     blocks 64..191: layer-1 fused input+recurrent, 32 rows x K=2048 in LDS
//     pipelined: grid-step s computes h0[t0+s] and h1[t0+s-1].
//     c-state in registers, h via 2-slot global rings, weights XOR-swizzled LDS.

typedef unsigned short ush;
typedef short bf16x8 __attribute__((ext_vector_type(8)));
typedef float f32x4 __attribute__((ext_vector_type(4)));

#define TT 512
#define NA 64
#define NB 128

__device__ __forceinline__ ush f2bf(float f) {
  __hip_bfloat16 h = __float2bfloat16(f);
  return *reinterpret_cast<ush*>(&h);
}
__device__ __forceinline__ float sigm(float x) { return 1.f / (1.f + __expf(-x)); }

// ---------------------------------------------------------------------------
// Wb[j][k] = bf16(W[j][off+k]), 1024 cols. grid 4096, 256 thr x 4 elems.
// ---------------------------------------------------------------------------
__global__ __launch_bounds__(256) void cast_w1k(const float* __restrict__ W,
                                                ush* __restrict__ Wb, int off) {
  int j = blockIdx.x;
  int k = threadIdx.x * 4;
  float4 v = *(const float4*)(W + (size_t)j * 2048 + off + k);
  ushort4 o;
  o.x = f2bf(v.x); o.y = f2bf(v.y); o.z = f2bf(v.z); o.w = f2bf(v.w);
  *(ushort4*)(Wb + (size_t)j * 1024 + k) = o;
}

// Full-width cast of W1 [4096][2048] fp32 -> bf16.
__global__ __launch_bounds__(512) void cast_w2k(const float* __restrict__ W,
                                                ush* __restrict__ Wb) {
  int j = blockIdx.x;
  int k = threadIdx.x * 4;
  float4 v = *(const float4*)(W + (size_t)j * 2048 + k);
  ushort4 o;
  o.x = f2bf(v.x); o.y = f2bf(v.y); o.z = f2bf(v.z); o.w = f2bf(v.w);
  *(ushort4*)(Wb + (size_t)j * 2048 + k) = o;
}

__global__ __launch_bounds__(256) void zero4k(uint4* __restrict__ p) {
  p[blockIdx.x * 256 + threadIdx.x] = uint4{0, 0, 0, 0};
}

// ---------------------------------------------------------------------------
// 128x128 MFMA GEMM: G[r][j] = bias[j] + sum_{k<1024} A[r][k]*Wb[j][k].
// A row r=(lt*32+b) -> x[b][t0+lt][*] fp32 (cvt in staging). B = bf16 Wb rows.
// ---------------------------------------------------------------------------
__global__ __launch_bounds__(256) void gemm128(
    const float* __restrict__ xA, const ush* __restrict__ Wb,
    const float* __restrict__ bias, float* __restrict__ G, int t0) {
  __shared__ ush As[128][88];
  __shared__ ush Bs[128][88];
  int tid = threadIdx.x;
  int bn = blockIdx.x, bm = blockIdx.y;
  int srow = tid >> 1;
  int shalf = (tid & 1) * 32;
  int lane = tid & 63, quad = lane >> 4, l15 = lane & 15;
  int w = tid >> 6;
  int m_base = (w >> 1) * 64, n_base = (w & 1) * 64;

  int r = bm * 128 + srow;
  const float* axf = xA + ((size_t)(r & 31) * TT + t0 + (r >> 5)) * 1024;
  const ush* wrow = Wb + (size_t)(bn * 128 + srow) * 1024;

  f32x4 acc[4][4];
#pragma unroll
  for (int i = 0; i < 4; ++i)
#pragma unroll
    for (int j = 0; j < 4; ++j) acc[i][j] = f32x4{0.f, 0.f, 0.f, 0.f};

  for (int k0 = 0; k0 < 1024; k0 += 64) {
    {
      const float* p = axf + k0 + shalf;
      ush* d = &As[srow][shalf];
#pragma unroll
      for (int s = 0; s < 8; ++s) {
        float4 v = ((const float4*)p)[s];
        ushort4 o;
        o.x = f2bf(v.x); o.y = f2bf(v.y); o.z = f2bf(v.z); o.w = f2bf(v.w);
        ((ushort4*)d)[s] = o;
      }
    }
    {
      const uint4* p = (const uint4*)(wrow + k0 + shalf);
      uint4* d = (uint4*)&Bs[srow][shalf];
#pragma unroll
      for (int s = 0; s < 4; ++s) d[s] = p[s];
    }
    __syncthreads();
#pragma unroll
    for (int kc = 0; kc < 2; ++kc) {
      bf16x8 af[4], bf_[4];
#pragma unroll
      for (int i = 0; i < 4; ++i)
        af[i] = *(const bf16x8*)&As[m_base + i * 16 + l15][kc * 32 + quad * 8];
#pragma unroll
      for (int j = 0; j < 4; ++j)
        bf_[j] = *(const bf16x8*)&Bs[n_base + j * 16 + l15][kc * 32 + quad * 8];
#pragma unroll
      for (int i = 0; i < 4; ++i)
#pragma unroll
        for (int j = 0; j < 4; ++j)
          acc[i][j] = __builtin_amdgcn_mfma_f32_16x16x32_bf16(af[i], bf_[j],
                                                              acc[i][j], 0, 0, 0);
    }
    __syncthreads();
  }

#pragma unroll
  for (int j = 0; j < 4; ++j) {
    int col = bn * 128 + n_base + j * 16 + l15;
    float bj = bias[col];
#pragma unroll
    for (int i = 0; i < 4; ++i) {
      int row = bm * 128 + m_base + i * 16 + quad * 4;
#pragma unroll
      for (int reg = 0; reg < 4; ++reg)
        G[(size_t)(row + reg) * 4096 + col] = acc[i][j][reg] + bj;
    }
  }
}

// ---------------------------------------------------------------------------
// Persistent pipelined recurrence for one chunk of Tc steps.
// grid = 192 blocks x 512 threads, 1 block/CU (144 KB LDS), cooperative.
// ---------------------------------------------------------------------------
__global__ __launch_bounds__(512, 2) void lstm_persist(
    const float* __restrict__ G0,   // [Tc*32][4096] fp32, bias included
    const ush* __restrict__ Wh0,    // [4096][1024] bf16
    const ush* __restrict__ W1b,    // [4096][2048] bf16
    const float* __restrict__ b1,   // [4096] fp32
    ush* __restrict__ h0r,          // 2 slots x [32][1024] bf16
    ush* __restrict__ h1r,          // 2 slots x [32][1024] bf16
    float* __restrict__ cst,        // [2][32][1024] fp32 (persist across chunks)
    float* __restrict__ OUT,        // outputs base [32][512][1024]
    float* __restrict__ hno,        // h_n base [2][32][1024]
    float* __restrict__ cno,        // c_n base [2][32][1024]
    int t0, int Tc, int last) {
  __shared__ ush wl[65536];         // 128 KB weight slice (XOR-swizzled rows)
  __shared__ float pg[8][32][16];   // 16 KB partial-gate exchange
  char* wlc = (char*)wl;

  cg::grid_group grid = cg::this_grid();
  int tid = threadIdx.x;
  int bid = blockIdx.x;
  int nsteps = Tc + (last ? 1 : 0);

  int w = tid >> 6, lane = tid & 63, quad = lane >> 4, l15 = lane & 15;

  if (bid < NA) {
    // ================= layer-0 block: 16 cols x 4 gates, K=1024 ============
    int c0 = bid * 16;
    {
      int r32 = tid >> 3, seg = tid & 7;  // 64 rows, 8 segs of 128 elems
      int grow = (r32 >> 4) * 1024 + c0 + (r32 & 15);
      const uint4* src = (const uint4*)(Wh0 + (size_t)grow * 1024 + seg * 128);
      int base = r32 * 2048;
      int xo = (r32 & 7) << 4;
#pragma unroll
      for (int i = 0; i < 16; ++i)
        *(uint4*)(wlc + base + ((seg * 256 + i * 16) ^ xo)) = src[i];
    }
    __syncthreads();

    int g = w & 3, kh = w >> 2;
    int r32 = g * 16 + l15;
    const char* bbase = wlc + r32 * 2048;
    int xo = (r32 & 7) << 4;
    int kb0 = (kh * 512 + quad * 8) * 2;

    int b = tid >> 4, c = tid & 15;
    int ci = b * 1024 + c0 + c;
    float creg = (t0 > 0) ? cst[ci] : 0.f;

    for (int s = 0; s < nsteps; ++s) {
      if (s < Tc) {
        int t = t0 + s;
        const ush* hp = h0r + (size_t)((t - 1) & 1) * 32768;
        const ush* ap0 = hp + (size_t)l15 * 1024 + kh * 512 + quad * 8;
        const ush* ap1 = ap0 + 16 * 1024;
        f32x4 acc0 = {0.f, 0.f, 0.f, 0.f}, acc1 = {0.f, 0.f, 0.f, 0.f};
#pragma unroll
        for (int ch = 0; ch < 16; ++ch) {
          bf16x8 bv = *(const bf16x8*)(bbase + ((kb0 + ch * 64) ^ xo));
          bf16x8 a0 = *(const bf16x8*)(ap0 + ch * 32);
          bf16x8 a1 = *(const bf16x8*)(ap1 + ch * 32);
          acc0 = __builtin_amdgcn_mfma_f32_16x16x32_bf16(a0, bv, acc0, 0, 0, 0);
          acc1 = __builtin_amdgcn_mfma_f32_16x16x32_bf16(a1, bv, acc1, 0, 0, 0);
        }
#pragma unroll
        for (int reg = 0; reg < 4; ++reg) {
          pg[w][quad * 4 + reg][l15] = acc0[reg];
          pg[w][16 + quad * 4 + reg][l15] = acc1[reg];
        }
        __syncthreads();
        const float* grow = G0 + (size_t)(s * 32 + b) * 4096 + c0 + c;
        float s0 = grow[0]    + pg[0][b][c] + pg[4][b][c];
        float s1 = grow[1024] + pg[1][b][c] + pg[5][b][c];
        float s2 = grow[2048] + pg[2][b][c] + pg[6][b][c];
        float s3 = grow[3072] + pg[3][b][c] + pg[7][b][c];
        float fg = sigm(s0), ig = sigm(s1), gv = tanhf(s2), og = sigm(s3);
        creg = fg * creg + ig * gv;
        float hnv = og * tanhf(creg);
        h0r[(size_t)(t & 1) * 32768 + ci] = f2bf(hnv);
        if (t == TT - 1) hno[ci] = hnv;
        __syncthreads();
      }
      grid.sync();
    }
    cst[ci] = creg;
    if (last) cno[ci] = creg;
  } else {
    // ============ layer-1 block: 8 cols x 4 gates, K=2048 (h0 ++ h1) =======
    int bidb = bid - NA;
    int c0b = bidb * 8;
    {
      int r32 = tid >> 4, seg = tid & 15;  // 32 rows, 16 segs of 128 elems
      int grow = (r32 >> 3) * 1024 + c0b + (r32 & 7);
      const uint4* src = (const uint4*)(W1b + (size_t)grow * 2048 + seg * 128);
      int base = r32 * 4096;
      int xo = (r32 & 7) << 4;
#pragma unroll
      for (int i = 0; i < 16; ++i)
        *(uint4*)(wlc + base + ((seg * 256 + i * 16) ^ xo)) = src[i];
    }
    __syncthreads();

    int rh = w & 1, kq = w >> 1;
    int r32 = rh * 16 + l15;
    const char* bbase = wlc + r32 * 4096;
    int xo = (r32 & 7) << 4;
    int kb0 = (kq * 512 + quad * 8) * 2;

    bool pw = tid < 256;
    int b = tid >> 3, cc = tid & 7;
    int ci = 0;
    float creg = 0.f;
    float biasr[4] = {0.f, 0.f, 0.f, 0.f};
    if (pw) {
      ci = b * 1024 + c0b + cc;
      creg = (t0 > 0) ? cst[32768 + ci] : 0.f;
#pragma unroll
      for (int g = 0; g < 4; ++g) biasr[g] = b1[g * 1024 + c0b + cc];
    }

    for (int s = 0; s < nsteps; ++s) {
      int t1 = t0 + s - 1;
      if (t1 >= 0 && t1 < TT) {
        const ush* h0p = h0r + (size_t)(t1 & 1) * 32768;
        const ush* h1p = h1r + (size_t)((t1 - 1) & 1) * 32768;
        const ush* ap0;
        if (kq < 2)
          ap0 = h0p + (size_t)l15 * 1024 + kq * 512 + quad * 8;
        else
          ap0 = h1p + (size_t)l15 * 1024 + (kq - 2) * 512 + quad * 8;
        const ush* ap1 = ap0 + 16 * 1024;
        f32x4 acc0 = {0.f, 0.f, 0.f, 0.f}, acc1 = {0.f, 0.f, 0.f, 0.f};
#pragma unroll
        for (int ch = 0; ch < 16; ++ch) {
          bf16x8 bv = *(const bf16x8*)(bbase + ((kb0 + ch * 64) ^ xo));
          bf16x8 a0 = *(const bf16x8*)(ap0 + ch * 32);
          bf16x8 a1 = *(const bf16x8*)(ap1 + ch * 32);
          acc0 = __builtin_amdgcn_mfma_f32_16x16x32_bf16(a0, bv, acc0, 0, 0, 0);
          acc1 = __builtin_amdgcn_mfma_f32_16x16x32_bf16(a1, bv, acc1, 0, 0, 0);
        }
#pragma unroll
        for (int reg = 0; reg < 4; ++reg) {
          pg[w][quad * 4 + reg][l15] = acc0[reg];
          pg[w][16 + quad * 4 + reg][l15] = acc1[reg];
        }
        __syncthreads();
        if (pw) {
          float sg[4];
#pragma unroll
          for (int g = 0; g < 4; ++g) {
            int r = g * 8 + cc, rrh = r >> 4, ri = r & 15;
            sg[g] = biasr[g] + pg[rrh][b][ri] + pg[2 + rrh][b][ri] +
                    pg[4 + rrh][b][ri] + pg[6 + rrh][b][ri];
          }
          float fg = sigm(sg[0]), ig = sigm(sg[1]), gv = tanhf(sg[2]),
                og = sigm(sg[3]);
          creg = fg * creg + ig * gv;
          float hnv = og * tanhf(creg);
          h1r[(size_t)(t1 & 1) * 32768 + ci] = f2bf(hnv);
          OUT[((size_t)b * TT + t1) * 1024 + c0b + cc] = hnv;
          if (t1 == TT - 1) hno[32768 + ci] = hnv;
        }
        __syncthreads();
      }
      grid.sync();
    }
    if (pw) {
      cst[32768 + ci] = creg;
      if (last) cno[32768 + ci] = creg;
    }
  }
}

extern "C" void kernel_launch(void* const* d_in, const int* in_sizes, int n_in,
                              void* d_out, int out_size, void* d_ws, size_t ws_size,
                              hipStream_t stream) {
  const float* x = (const float*)d_in[0];
  const float* W0 = (const float*)d_in[1];
  const float* b0 = (const float*)d_in[2];
  const float* W1 = (const float*)d_in[3];
  const float* b1 = (const float*)d_in[4];
  float* OUT = (float*)d_out;

  // ws layout (bytes):
  //   Wxb0 [4096][1024] bf16 : 0        .. 8388608   (x-half of W0)
  //   Whb0 [4096][1024] bf16 : 8388608  .. 16777216  (h-half of W0)
  //   W1b  [4096][2048] bf16 : 16777216 .. 33554432
  //   h0r  2x[32][1024] bf16 : 33554432 .. 33685504
  //   h1r  2x[32][1024] bf16 : 33685504 .. 33816576
  //   cst  [2][32][1024] f32 : 33816576 .. 34078720
  //   G0   [Tc*32][4096] f32 : 34078720 ..
  int Tc = 4;
  {
    const int cand[5] = {64, 32, 16, 8, 4};
    for (int i = 0; i < 5; ++i) {
      size_t need = 34078720ull + (size_t)cand[i] * 32 * 4096 * 4;
      if (need <= ws_size) { Tc = cand[i]; break; }
    }
  }
  char* ws = (char*)d_ws;
  ush* Wxb0 = (ush*)ws;
  ush* Whb0 = (ush*)(ws + 8388608);
  ush* W1b = (ush*)(ws + 16777216);
  ush* h0r = (ush*)(ws + 33554432);
  ush* h1r = (ush*)(ws + 33685504);
  float* cst = (float*)(ws + 33816576);
  float* G = (float*)(ws + 34078720);

  cast_w1k<<<4096, 256, 0, stream>>>(W0, Wxb0, 0);
  cast_w1k<<<4096, 256, 0, stream>>>(W0, Whb0, 1024);
  cast_w2k<<<4096, 512, 0, stream>>>(W1, W1b);
  zero4k<<<64, 256, 0, stream>>>((uint4*)h0r);  // zeroes both rings (256 KB)

  float* hnp = OUT + 16777216;
  float* cnp = OUT + 16777216 + 65536;
  dim3 ggrid(32, (unsigned)(Tc * 32 / 128));

  const int NCH = TT / Tc;
  for (int ch = 0; ch < NCH; ++ch) {
    int t0v = ch * Tc;
    int lastv = (ch == NCH - 1) ? 1 : 0;
    gemm128<<<ggrid, 256, 0, stream>>>(x, Wxb0, b0, G, t0v);
    void* pargs[13] = {(void*)&G,   (void*)&Whb0, (void*)&W1b, (void*)&b1,
                       (void*)&h0r, (void*)&h1r,  (void*)&cst, (void*)&OUT,
                       (void*)&hnp, (void*)&cnp,  (void*)&t0v, (void*)&Tc,
                       (void*)&lastv};
    hipLaunchCooperativeKernel((void*)lstm_persist, dim3(NA + NB), dim3(512),
                               pargs, 0, stream);
  }
}

// Round 3
// 3505.583 us; speedup vs baseline: 4.6775x; 4.6775x over previous
//
#include <hip/hip_runtime.h>
#include <hip/hip_bf16.h>
#include <cstdint>
#include <cstddef>

// B=32, T=512, I=H=1024, L=2, gates 4H=4096. fp32 in/out.
// d_out fp32: outputs[32][512][1024] ++ h_n[2][32][1024] ++ c_n[2][32][1024].
// Per chunk of Tc steps:
//   gemm128: G0 = x@Wx0^T + b0 (bf16 MFMA, fp32 out; Wx0 pre-cast bf16)
//   lstm_persist (cooperative for co-residency; NO grid.sync):
//     flag-based producer/consumer sync via agent-scope atomics,
//     h exchanged through 8-deep rings with L2-bypass (sc1) atomics,
//     weights pre-swizzled into per-wave MFMA fragment order (L2-cached),
//     h staged per-step into XOR-swizzled LDS.

typedef unsigned short ush;
typedef short bf16x8 __attribute__((ext_vector_type(8)));
typedef float f32x4 __attribute__((ext_vector_type(4)));
typedef unsigned long long u64;

#define TT 512
#define NA 64
#define NB 128
#define RING 8

__device__ __forceinline__ ush f2bf(float f) {
  __hip_bfloat16 h = __float2bfloat16(f);
  return *reinterpret_cast<ush*>(&h);
}
__device__ __forceinline__ float sigm(float x) { return 1.f / (1.f + __expf(-x)); }

__device__ __forceinline__ unsigned int aload(const unsigned int* p) {
  return __hip_atomic_load(p, __ATOMIC_RELAXED, __HIP_MEMORY_SCOPE_AGENT);
}
__device__ __forceinline__ void astore(unsigned int* p, unsigned int v) {
  __hip_atomic_store(p, v, __ATOMIC_RELAXED, __HIP_MEMORY_SCOPE_AGENT);
}
__device__ __forceinline__ u64 aload64(const u64* p) {
  return __hip_atomic_load(p, __ATOMIC_RELAXED, __HIP_MEMORY_SCOPE_AGENT);
}

// ---------------------------------------------------------------------------
// Wb[j][k] = bf16(W[j][off+k]), 1024 cols (plain layout, for gemm128 B).
// ---------------------------------------------------------------------------
__global__ __launch_bounds__(256) void cast_w1k(const float* __restrict__ W,
                                                ush* __restrict__ Wb, int off) {
  int j = blockIdx.x;
  int k = threadIdx.x * 4;
  float4 v = *(const float4*)(W + (size_t)j * 2048 + off + k);
  ushort4 o;
  o.x = f2bf(v.x); o.y = f2bf(v.y); o.z = f2bf(v.z); o.w = f2bf(v.w);
  *(ushort4*)(Wb + (size_t)j * 1024 + k) = o;
}

// ---------------------------------------------------------------------------
// Pre-swizzle W0 h-half into per-(block,wave,chunk,lane) fragment order.
// n < 524288; elem base = n*8. lane=n&63, ch=(n>>6)&15, w=(n>>10)&7, i=n>>13.
// ---------------------------------------------------------------------------
__global__ __launch_bounds__(256) void swz0(const float* __restrict__ W,
                                            ush* __restrict__ D) {
  int n = blockIdx.x * 256 + threadIdx.x;
  int lane = n & 63, ch = (n >> 6) & 15, w = (n >> 10) & 7, i = n >> 13;
  int l15 = lane & 15, quad = lane >> 4, g = w & 3, kh = w >> 2;
  int row = g * 1024 + i * 16 + l15;
  int col = 1024 + kh * 512 + ch * 32 + quad * 8;
  const float* src = W + (size_t)row * 2048 + col;
  float4 v0 = ((const float4*)src)[0];
  float4 v1 = ((const float4*)src)[1];
  ushort4 o0, o1;
  o0.x = f2bf(v0.x); o0.y = f2bf(v0.y); o0.z = f2bf(v0.z); o0.w = f2bf(v0.w);
  o1.x = f2bf(v1.x); o1.y = f2bf(v1.y); o1.z = f2bf(v1.z); o1.w = f2bf(v1.w);
  *(ushort4*)(D + (size_t)n * 8) = o0;
  *(ushort4*)(D + (size_t)n * 8 + 4) = o1;
}

// ---------------------------------------------------------------------------
// Pre-swizzle W1 (full K=2048). n < 1048576. j=n>>13 (128 blocks).
// staged row r32 = (w&1)*16 + l15 -> W1 row (r32>>3)*1024 + j*8 + (r32&7).
// ---------------------------------------------------------------------------
__global__ __launch_bounds__(256) void swz1(const float* __restrict__ W,
                                            ush* __restrict__ D) {
  int n = blockIdx.x * 256 + threadIdx.x;
  int lane = n & 63, ch = (n >> 6) & 15, w = (n >> 10) & 7, j = n >> 13;
  int l15 = lane & 15, quad = lane >> 4, rh = w & 1, kq = w >> 1;
  int r32 = rh * 16 + l15;
  int row = (r32 >> 3) * 1024 + j * 8 + (r32 & 7);
  int col = kq * 512 + ch * 32 + quad * 8;
  const float* src = W + (size_t)row * 2048 + col;
  float4 v0 = ((const float4*)src)[0];
  float4 v1 = ((const float4*)src)[1];
  ushort4 o0, o1;
  o0.x = f2bf(v0.x); o0.y = f2bf(v0.y); o0.z = f2bf(v0.z); o0.w = f2bf(v0.w);
  o1.x = f2bf(v1.x); o1.y = f2bf(v1.y); o1.z = f2bf(v1.z); o1.w = f2bf(v1.w);
  *(ushort4*)(D + (size_t)n * 8) = o0;
  *(ushort4*)(D + (size_t)n * 8 + 4) = o1;
}

__global__ __launch_bounds__(256) void zeroreg(uint4* __restrict__ p) {
  p[blockIdx.x * 256 + threadIdx.x] = uint4{0, 0, 0, 0};
}

// ---------------------------------------------------------------------------
// 128x128 MFMA GEMM: G[r][j] = bias[j] + sum_k A[r][k]*Wb[j][k]. (unchanged)
// ---------------------------------------------------------------------------
__global__ __launch_bounds__(256) void gemm128(
    const float* __restrict__ xA, const ush* __restrict__ Wb,
    const float* __restrict__ bias, float* __restrict__ G, int t0) {
  __shared__ ush As[128][88];
  __shared__ ush Bs[128][88];
  int tid = threadIdx.x;
  int bn = blockIdx.x, bm = blockIdx.y;
  int srow = tid >> 1;
  int shalf = (tid & 1) * 32;
  int lane = tid & 63, quad = lane >> 4, l15 = lane & 15;
  int w = tid >> 6;
  int m_base = (w >> 1) * 64, n_base = (w & 1) * 64;

  int r = bm * 128 + srow;
  const float* axf = xA + ((size_t)(r & 31) * TT + t0 + (r >> 5)) * 1024;
  const ush* wrow = Wb + (size_t)(bn * 128 + srow) * 1024;

  f32x4 acc[4][4];
#pragma unroll
  for (int i = 0; i < 4; ++i)
#pragma unroll
    for (int j = 0; j < 4; ++j) acc[i][j] = f32x4{0.f, 0.f, 0.f, 0.f};

  for (int k0 = 0; k0 < 1024; k0 += 64) {
    {
      const float* p = axf + k0 + shalf;
      ush* d = &As[srow][shalf];
#pragma unroll
      for (int s = 0; s < 8; ++s) {
        float4 v = ((const float4*)p)[s];
        ushort4 o;
        o.x = f2bf(v.x); o.y = f2bf(v.y); o.z = f2bf(v.z); o.w = f2bf(v.w);
        ((ushort4*)d)[s] = o;
      }
    }
    {
      const uint4* p = (const uint4*)(wrow + k0 + shalf);
      uint4* d = (uint4*)&Bs[srow][shalf];
#pragma unroll
      for (int s = 0; s < 4; ++s) d[s] = p[s];
    }
    __syncthreads();
#pragma unroll
    for (int kc = 0; kc < 2; ++kc) {
      bf16x8 af[4], bf_[4];
#pragma unroll
      for (int i = 0; i < 4; ++i)
        af[i] = *(const bf16x8*)&As[m_base + i * 16 + l15][kc * 32 + quad * 8];
#pragma unroll
      for (int j = 0; j < 4; ++j)
        bf_[j] = *(const bf16x8*)&Bs[n_base + j * 16 + l15][kc * 32 + quad * 8];
#pragma unroll
      for (int i = 0; i < 4; ++i)
#pragma unroll
        for (int j = 0; j < 4; ++j)
          acc[i][j] = __builtin_amdgcn_mfma_f32_16x16x32_bf16(af[i], bf_[j],
                                                              acc[i][j], 0, 0, 0);
    }
    __syncthreads();
  }

#pragma unroll
  for (int j = 0; j < 4; ++j) {
    int col = bn * 128 + n_base + j * 16 + l15;
    float bj = bias[col];
#pragma unroll
    for (int i = 0; i < 4; ++i) {
      int row = bm * 128 + m_base + i * 16 + quad * 4;
#pragma unroll
      for (int reg = 0; reg < 4; ++reg)
        G[(size_t)(row + reg) * 4096 + col] = acc[i][j][reg] + bj;
    }
  }
}

// ---------------------------------------------------------------------------
// Persistent flag-synced recurrence for one chunk of Tc steps.
// 192 blocks x 512 thr, cooperative launch (co-residency only; no grid.sync).
// ---------------------------------------------------------------------------
__global__ __launch_bounds__(512, 2) void lstm_persist(
    const float* __restrict__ G0, const ush* __restrict__ Wsw0,
    const ush* __restrict__ Wsw1, const float* __restrict__ b1,
    ush* __restrict__ h0r, ush* __restrict__ h1r,
    unsigned int* __restrict__ flg,  // prog0 @ [i*16]; prog1 @ [1024 + j*16]
    float* __restrict__ cst, float* __restrict__ OUT,
    float* __restrict__ hno, float* __restrict__ cno,
    int t0, int Tc, int last) {
  __shared__ ush hbuf[65536];       // 128 KB (layer-0 uses first 64 KB)
  __shared__ float pg[8][32][16];   // 16 KB partial-gate exchange
  char* hb = (char*)hbuf;

  int tid = threadIdx.x;
  int bid = blockIdx.x;
  int w = tid >> 6, lane = tid & 63, quad = lane >> 4, l15 = lane & 15;
  unsigned int* prog0 = flg;
  unsigned int* prog1 = flg + 1024;

  if (bid < NA) {
    // ================= layer-0 block: 16 cols x 4 gates, K=1024 ============
    int c0 = bid * 16;
    const ush* wp = Wsw0 + ((size_t)bid * 8 + w) * 8192 + (size_t)lane * 8;
    int b = tid >> 4, c = tid & 15;
    int ci = b * 1024 + c0 + c;
    float creg = (t0 > 0) ? cst[ci] : 0.f;
    int m1c = t0;  // cached min(prog1) lower bound (wave-0 lanes)

    for (int s = 0; s < Tc; ++s) {
      int t = t0 + s;
      if (tid < 64) {
        while ((int)aload(&prog0[tid * 16]) < t) {}
        while (m1c < t - (RING - 1)) {  // ring-clobber guard (lazy)
          int m = (int)aload(&prog1[tid * 16]);
          m = min(m, (int)aload(&prog1[(64 + tid) * 16]));
#pragma unroll
          for (int d = 1; d < 64; d <<= 1) m = min(m, __shfl_xor(m, d));
          m1c = m;
        }
      }
      __syncthreads();
      {  // stage h0[t-1] -> swizzled LDS
        const u64* src = (const u64*)(h0r + (size_t)((t - 1) & (RING - 1)) * 32768);
#pragma unroll
        for (int s2 = 0; s2 < 8; ++s2) {
          int gi = s2 * 512 + tid;
          u64 lo = aload64(src + (size_t)gi * 2);
          u64 hi = aload64(src + (size_t)gi * 2 + 1);
          int r = gi >> 7, kb = (gi & 127) * 16;
          u64* d = (u64*)(hb + r * 2048 + (kb ^ ((r & 7) << 4)));
          d[0] = lo; d[1] = hi;
        }
      }
      __syncthreads();
      f32x4 acc0 = {0.f, 0.f, 0.f, 0.f}, acc1 = {0.f, 0.f, 0.f, 0.f};
      {
        int kh = w >> 2;
        int kbase = kh * 1024 + quad * 16;
        int x0 = (l15 & 7) << 4;
        const char* a0p = hb + l15 * 2048;
        const char* a1p = hb + (16 + l15) * 2048;
#pragma unroll
        for (int ch = 0; ch < 16; ++ch) {
          int kb = kbase + ch * 64;
          bf16x8 bv = *(const bf16x8*)(wp + ch * 512);
          bf16x8 a0 = *(const bf16x8*)(a0p + (kb ^ x0));
          bf16x8 a1 = *(const bf16x8*)(a1p + (kb ^ x0));
          acc0 = __builtin_amdgcn_mfma_f32_16x16x32_bf16(a0, bv, acc0, 0, 0, 0);
          acc1 = __builtin_amdgcn_mfma_f32_16x16x32_bf16(a1, bv, acc1, 0, 0, 0);
        }
      }
#pragma unroll
      for (int reg = 0; reg < 4; ++reg) {
        pg[w][quad * 4 + reg][l15] = acc0[reg];
        pg[w][16 + quad * 4 + reg][l15] = acc1[reg];
      }
      __syncthreads();
      const float* grow = G0 + (size_t)(s * 32 + b) * 4096 + c0 + c;
      float s0 = grow[0]    + pg[0][b][c] + pg[4][b][c];
      float s1 = grow[1024] + pg[1][b][c] + pg[5][b][c];
      float s2 = grow[2048] + pg[2][b][c] + pg[6][b][c];
      float s3 = grow[3072] + pg[3][b][c] + pg[7][b][c];
      float fg = sigm(s0), ig = sigm(s1), gv = tanhf(s2), og = sigm(s3);
      creg = fg * creg + ig * gv;
      float hnv = og * tanhf(creg);
      float ho = __shfl_xor(hnv, 1);
      if (!(tid & 1)) {
        unsigned int pk = (unsigned int)f2bf(hnv) | ((unsigned int)f2bf(ho) << 16);
        ush* slot = h0r + (size_t)(t & (RING - 1)) * 32768;
        astore((unsigned int*)(slot + ci), pk);
      }
      if (t == TT - 1) hno[ci] = hnv;
      __syncthreads();  // drains all h stores (vmcnt) before flag
      if (tid == 0) astore(&prog0[bid * 16], (unsigned int)(t + 1));
    }
    cst[ci] = creg;
    if (last) cno[ci] = creg;
  } else {
    // ============ layer-1 block: 8 cols x 4 gates, K=2048 (h0 ++ h1) =======
    int jb = bid - NA;
    int c0b = jb * 8;
    const ush* wp = Wsw1 + ((size_t)jb * 8 + w) * 8192 + (size_t)lane * 8;
    bool pw = tid < 256;
    int b = tid >> 3, cc = tid & 7;
    int ci = b * 1024 + c0b + cc;  // meaningful only when pw
    float creg = 0.f;
    float biasr[4] = {0.f, 0.f, 0.f, 0.f};
    if (pw) {
      creg = (t0 > 0) ? cst[32768 + ci] : 0.f;
#pragma unroll
      for (int g = 0; g < 4; ++g) biasr[g] = b1[g * 1024 + c0b + cc];
    }

    for (int s = 0; s < Tc; ++s) {
      int t = t0 + s;
      if (tid < 64) {
        while ((int)aload(&prog0[tid * 16]) < t + 1) {}
        while ((int)aload(&prog1[tid * 16]) < t) {}
        while ((int)aload(&prog1[(64 + tid) * 16]) < t) {}
      }
      __syncthreads();
      {  // stage h0[t] and h1[t-1] -> swizzled LDS (128 KB)
        const u64* s0p = (const u64*)(h0r + (size_t)(t & (RING - 1)) * 32768);
        const u64* s1p = (const u64*)(h1r + (size_t)((t - 1) & (RING - 1)) * 32768);
#pragma unroll
        for (int s2 = 0; s2 < 16; ++s2) {
          const u64* src = (s2 < 8) ? s0p : s1p;
          int gi = (s2 & 7) * 512 + tid;
          u64 lo = aload64(src + (size_t)gi * 2);
          u64 hi = aload64(src + (size_t)gi * 2 + 1);
          int r = gi >> 7, kb = (gi & 127) * 16;
          u64* d = (u64*)(hb + ((s2 < 8) ? 0 : 65536) + r * 2048 +
                          (kb ^ ((r & 7) << 4)));
          d[0] = lo; d[1] = hi;
        }
      }
      __syncthreads();
      f32x4 acc0 = {0.f, 0.f, 0.f, 0.f}, acc1 = {0.f, 0.f, 0.f, 0.f};
      {
        int kq = w >> 1;
        int boff = (kq < 2) ? 0 : 65536;
        int kbase = (kq & 1) * 1024 + quad * 16;
        int x0 = (l15 & 7) << 4;
        const char* a0p = hb + boff + l15 * 2048;
        const char* a1p = a0p + 16 * 2048;
#pragma unroll
        for (int ch = 0; ch < 16; ++ch) {
          int kb = kbase + ch * 64;
          bf16x8 bv = *(const bf16x8*)(wp + ch * 512);
          bf16x8 a0 = *(const bf16x8*)(a0p + (kb ^ x0));
          bf16x8 a1 = *(const bf16x8*)(a1p + (kb ^ x0));
          acc0 = __builtin_amdgcn_mfma_f32_16x16x32_bf16(a0, bv, acc0, 0, 0, 0);
          acc1 = __builtin_amdgcn_mfma_f32_16x16x32_bf16(a1, bv, acc1, 0, 0, 0);
        }
      }
#pragma unroll
      for (int reg = 0; reg < 4; ++reg) {
        pg[w][quad * 4 + reg][l15] = acc0[reg];
        pg[w][16 + quad * 4 + reg][l15] = acc1[reg];
      }
      __syncthreads();
      if (pw) {
        float sg[4];
#pragma unroll
        for (int g = 0; g < 4; ++g) {
          int r = g * 8 + cc, rrh = r >> 4, ri = r & 15;
          sg[g] = biasr[g] + pg[rrh][b][ri] + pg[2 + rrh][b][ri] +
                  pg[4 + rrh][b][ri] + pg[6 + rrh][b][ri];
        }
        float fg = sigm(sg[0]), ig = sigm(sg[1]), gv = tanhf(sg[2]),
              og = sigm(sg[3]);
        creg = fg * creg + ig * gv;
        float hnv = og * tanhf(creg);
        float ho = __shfl_xor(hnv, 1);
        if (!(tid & 1)) {
          unsigned int pk = (unsigned int)f2bf(hnv) | ((unsigned int)f2bf(ho) << 16);
          ush* slot = h1r + (size_t)(t & (RING - 1)) * 32768;
          astore((unsigned int*)(slot + ci), pk);
        }
        OUT[((size_t)b * TT + t) * 1024 + c0b + cc] = hnv;
        if (t == TT - 1) hno[32768 + ci] = hnv;
      }
      __syncthreads();
      if (tid == 0) astore(&prog1[jb * 16], (unsigned int)(t + 1));
    }
    if (pw) {
      cst[32768 + ci] = creg;
      if (last) cno[32768 + ci] = creg;
    }
  }
}

extern "C" void kernel_launch(void* const* d_in, const int* in_sizes, int n_in,
                              void* d_out, int out_size, void* d_ws, size_t ws_size,
                              hipStream_t stream) {
  const float* x = (const float*)d_in[0];
  const float* W0 = (const float*)d_in[1];
  const float* b0 = (const float*)d_in[2];
  const float* W1 = (const float*)d_in[3];
  const float* b1 = (const float*)d_in[4];
  float* OUT = (float*)d_out;

  // ws layout (bytes):
  //   Wxb0 [4096][1024] bf16 : 0        (gemm B, x-half of W0)
  //   Wsw0 swizzled 8 MB     : 8388608
  //   Wsw1 swizzled 16 MB    : 16777216
  //   h0r  RINGx64KB         : 33554432
  //   h1r  RINGx64KB         : 34078720
  //   flg  16 KB             : 34603008
  //   cst  [2][32][1024] f32 : 34619392
  //   G0   [Tc*32][4096] f32 : 34881536
  int Tc = 4;
  {
    const int cand[8] = {512, 256, 128, 64, 32, 16, 8, 4};
    for (int i = 0; i < 8; ++i) {
      size_t need = 34881536ull + (size_t)cand[i] * 524288;
      if (need <= ws_size) { Tc = cand[i]; break; }
    }
  }
  char* ws = (char*)d_ws;
  ush* Wxb0 = (ush*)ws;
  ush* Wsw0 = (ush*)(ws + 8388608);
  ush* Wsw1 = (ush*)(ws + 16777216);
  ush* h0r = (ush*)(ws + 33554432);
  ush* h1r = (ush*)(ws + 34078720);
  unsigned int* flg = (unsigned int*)(ws + 34603008);
  float* cst = (float*)(ws + 34619392);
  float* G = (float*)(ws + 34881536);

  cast_w1k<<<4096, 256, 0, stream>>>(W0, Wxb0, 0);
  swz0<<<2048, 256, 0, stream>>>(W0, Wsw0);
  swz1<<<4096, 256, 0, stream>>>(W1, Wsw1);
  zeroreg<<<260, 256, 0, stream>>>((uint4*)(ws + 33554432));  // rings + flags

  float* hnp = OUT + 16777216;
  float* cnp = OUT + 16777216 + 65536;
  dim3 ggrid(32, (unsigned)(Tc * 32 / 128));

  const int NCH = TT / Tc;
  for (int ch = 0; ch < NCH; ++ch) {
    int t0v = ch * Tc;
    int lastv = (ch == NCH - 1) ? 1 : 0;
    gemm128<<<ggrid, 256, 0, stream>>>(x, Wxb0, b0, G, t0v);
    void* pargs[14] = {(void*)&G,    (void*)&Wsw0, (void*)&Wsw1, (void*)&b1,
                       (void*)&h0r,  (void*)&h1r,  (void*)&flg,  (void*)&cst,
                       (void*)&OUT,  (void*)&hnp,  (void*)&cnp,  (void*)&t0v,
                       (void*)&Tc,   (void*)&lastv};
    hipLaunchCooperativeKernel((void*)lstm_persist, dim3(NA + NB), dim3(512),
                               pargs, 0, stream);
  }
}